// Round 1
// baseline (185.321 us; speedup 1.0000x reference)
//
#include <hip/hip_runtime.h>

// TaylorFeatureMap: x (2,16,2048,64) fp32 -> out (2,16,2048,2145) fp32
// Row layout per vector v:
//   [0]        = 1
//   [1..64]    = x[i] / 8^0.5^0.5   (x / head_dim^0.25)
//   [65..128]  = x[i]^2 / (8*sqrt(2))
//   [129..2144]= x[i]*x[j] / 8, (i,j) = triu_indices(64, k=1) row-major

#define D 64
#define ROW 2145
#define OFFD_BASE 129

__global__ __launch_bounds__(256) void taylor_fm_kernel(
    const float* __restrict__ x, float* __restrict__ out) {
    const int v = blockIdx.x;

    __shared__ float xs[D];
    const float* xrow = x + (size_t)v * D;
    if (threadIdx.x < D / 4) {
        reinterpret_cast<float4*>(xs)[threadIdx.x] =
            reinterpret_cast<const float4*>(xrow)[threadIdx.x];
    }
    __syncthreads();

    const float inv_rrd   = 0.35355339059327373f;   // 1/8^0.5  (= 1/64^0.25)
    const float inv_rd_r2 = 0.08838834764831845f;   // 1/(8*sqrt(2))
    const float inv_rd    = 0.125f;                 // 1/8

    float* orow = out + (size_t)v * ROW;

    for (int k = threadIdx.x; k < ROW; k += 256) {
        float val;
        if (k == 0) {
            val = 1.0f;
        } else if (k < 65) {
            val = xs[k - 1] * inv_rrd;
        } else if (k < OFFD_BASE) {
            float a = xs[k - 65];
            val = a * a * inv_rd_r2;
        } else {
            int t = k - OFFD_BASE;                 // 0 .. 2015
            // i = floor((127 - sqrt(127^2 - 8t)) / 2); C(i) = i*(127-i)/2
            float disc = sqrtf((float)(16129 - 8 * t));
            int i = (int)((127.0f - disc) * 0.5f);
            int Ci = (i * (127 - i)) >> 1;
            if (t < Ci) {                          // rounding fixup (down)
                --i;
                Ci = (i * (127 - i)) >> 1;
            } else {
                int Ci1 = ((i + 1) * (126 - i)) >> 1;
                if (t >= Ci1) {                    // rounding fixup (up)
                    ++i;
                    Ci = Ci1;
                }
            }
            int j = t - Ci + i + 1;
            val = xs[i] * xs[j] * inv_rd;
        }
        orow[k] = val;
    }
}

extern "C" void kernel_launch(void* const* d_in, const int* in_sizes, int n_in,
                              void* d_out, int out_size, void* d_ws, size_t ws_size,
                              hipStream_t stream) {
    const float* x = (const float*)d_in[0];
    float* out = (float*)d_out;
    int nrows = in_sizes[0] / D;   // 65536
    taylor_fm_kernel<<<nrows, 256, 0, stream>>>(x, out);
}

// Round 2
// 141.178 us; speedup vs baseline: 1.3127x; 1.3127x over previous
//
#include <hip/hip_runtime.h>

// TaylorFeatureMap: x (2,16,2048,64) fp32 -> out (2,16,2048,2145) fp32
// Row layout per vector v:
//   [0]        = 1
//   [1..64]    = x[i] / 64^0.25
//   [65..128]  = x[i]^2 / (8*sqrt(2))
//   [129..2144]= x[i]*x[j] / 8, (i,j) = triu_indices(64, k=1) row-major
//
// One wave (64 lanes) per row. Lane l holds x[l]; the i-loop is fully
// unrolled so the broadcast of x[i] is a v_readlane with an immediate lane
// index (no LDS, no ds_bpermute). Triangle segment for row i is stored by
// lanes l > i at contiguous addresses -> coalesced masked store.

#define D 64
#define ROW 2145
#define OFFD_BASE 129

__global__ __launch_bounds__(256) void taylor_fm_kernel(
    const float* __restrict__ x, float* __restrict__ out) {
    const int wave = threadIdx.x >> 6;
    const int lane = threadIdx.x & 63;
    const int row  = blockIdx.x * 4 + wave;

    const float xl = x[(size_t)row * D + lane];

    const float inv_rrd   = 0.35355339059327373f;   // 1/64^0.25
    const float inv_rd_r2 = 0.08838834764831845f;   // 1/(8*sqrt(2))
    const float inv_rd    = 0.125f;                 // 1/8 (exact pow2)

    float* orow = out + (size_t)row * ROW;

    if (lane == 0) orow[0] = 1.0f;
    orow[1 + lane]  = xl * inv_rrd;
    orow[65 + lane] = xl * xl * inv_rd_r2;

    // Pre-scale one operand by the exact power-of-two 1/8 so
    // (x_i/8)*x_j == (x_i*x_j)/8 bit-exactly.
    const float xls = xl * inv_rd;

    float* tri = orow + OFFD_BASE;
#pragma unroll
    for (int i = 0; i < 63; ++i) {
        const int Ci = (i * (127 - i)) >> 1;        // start of row i's segment
        float xi = __uint_as_float(
            __builtin_amdgcn_readlane(__float_as_uint(xls), i));
        if (lane > i) {
            tri[Ci - i - 1 + lane] = xi * xl;
        }
    }
}

extern "C" void kernel_launch(void* const* d_in, const int* in_sizes, int n_in,
                              void* d_out, int out_size, void* d_ws, size_t ws_size,
                              hipStream_t stream) {
    const float* x = (const float*)d_in[0];
    float* out = (float*)d_out;
    int nrows = in_sizes[0] / D;        // 65536
    taylor_fm_kernel<<<nrows / 4, 256, 0, stream>>>(x, out);
}

// Round 3
// 114.123 us; speedup vs baseline: 1.6239x; 1.2371x over previous
//
#include <hip/hip_runtime.h>

// TaylorFeatureMap: x (2,16,2048,64) fp32 -> out (2,16,2048,2145) fp32
// Row layout per vector v:
//   [0]        = 1
//   [1..64]    = x[i] / 64^0.25
//   [65..128]  = x[i]^2 / (8*sqrt(2))
//   [129..2144]= x[i]*x[j] / 8, (i,j) = triu_indices(64, k=1) row-major
//
// Structure: 4 waves/block, one row per wave, computed into LDS via
// readlane-broadcast + masked contiguous ds_write (conflict-free). Then the
// block streams its 4-row chunk (34,320 B = 2145 float4, 16B-aligned because
// 4*2145*4 % 16 == 0) to global with dense aligned dwordx4 stores — fixes the
// R1 bottleneck (masked half-empty dword stores => 2x L2 write transactions).

#define D 64
#define ROW 2145
#define OFFD_BASE 129
#define RPB 4                      // rows per block (= waves per block)

__global__ __launch_bounds__(256) void taylor_fm_kernel(
    const float* __restrict__ x, float* __restrict__ out) {
    __shared__ __align__(16) float buf[RPB * ROW];   // 34,320 B

    const int wave = threadIdx.x >> 6;
    const int lane = threadIdx.x & 63;
    const int row  = blockIdx.x * RPB + wave;

    const float xl = x[(size_t)row * D + lane];

    const float inv_rrd   = 0.35355339059327373f;   // 1/64^0.25
    const float inv_rd_r2 = 0.08838834764831845f;   // 1/(8*sqrt(2))

    float* brow = buf + wave * ROW;
    if (lane == 0) brow[0] = 1.0f;
    brow[1 + lane]  = xl * inv_rrd;
    brow[65 + lane] = xl * xl * inv_rd_r2;

    // Pre-scale by exact pow2 1/8 so (x_i/8)*x_j == (x_i*x_j)/8 bit-exactly.
    const float xls = xl * 0.125f;

    float* tri = brow + OFFD_BASE;
#pragma unroll
    for (int i = 0; i < 63; ++i) {
        const int Ci = (i * (127 - i)) >> 1;        // start of row i's segment
        float xi = __uint_as_float(
            __builtin_amdgcn_readlane(__float_as_uint(xls), i));
        if (lane > i) {
            tri[Ci - i - 1 + lane] = xi * xl;
        }
    }

    __syncthreads();

    // Dense aligned float4 stream: 2145 float4 per block.
    const float4* b4 = reinterpret_cast<const float4*>(buf);
    float4* o4 = reinterpret_cast<float4*>(out + (size_t)blockIdx.x * (RPB * ROW));
    int q = threadIdx.x;
#pragma unroll
    for (int k = 0; k < 8; ++k, q += 256) {
        o4[q] = b4[q];
    }
    if (q < RPB * ROW / 4) {       // tail: 2145 - 8*256 = 97 float4
        o4[q] = b4[q];
    }
}

extern "C" void kernel_launch(void* const* d_in, const int* in_sizes, int n_in,
                              void* d_out, int out_size, void* d_ws, size_t ws_size,
                              hipStream_t stream) {
    const float* x = (const float*)d_in[0];
    float* out = (float*)d_out;
    int nrows = in_sizes[0] / D;        // 65536
    taylor_fm_kernel<<<nrows / RPB, 256, 0, stream>>>(x, out);
}